// Round 1
// baseline (2228.342 us; speedup 1.0000x reference)
//
#include <hip/hip_runtime.h>

// MLA forward, MI355X gfx950. Round 0: correctness-first bf16-MFMA pipeline.
// H=128 DN=128 DR=64 DV=128 RQ=1536 RKV=512 HSZ=5120 S=1024
//
// Pipeline:
//  1. cast hidden fp32 -> bf16 (ws)
//  2. gemm1:   h_bf(1024x5120) @ Wq_c  -> q_c fp32 (ws)
//  3. gemm_kv: h_bf @ Wkv_c            -> ckv fp32 (d_out #2, raw pre-norm)
//  4. rmsnorm q_c (W=1536)             -> q_n bf16
//  5. rmsnorm ckv[:, :512]             -> kv_n bf16
//  6. gemm2:   q_n @ Wq_d              -> q bf16 (1024 x 24576)  [s, h*192+d]
//  7. gemm3:   kv_n @ Wkv_d            -> kv bf16 (1024 x 32768) [s, h*256+d]
//  8. rope_q (in-place on q rope cols), rope_k (ckv -> krope bf16)
//  9. transpose V part of kv -> vt[h][dv][s] bf16 (for contiguous PV B-frags)
// 10. flash attention (BQ=64, BKV=64, online softmax fp32) -> attn_out bf16
// 11. gemm4:  attn_out @ Wo            -> out fp32 (d_out #1)
//
// MFMA 16x16x32 bf16. Layouts (HW-verified per guide):
//   A[m=lane&15][k=quad*8+j], B[k=quad*8+j][n=lane&15],
//   C/D: col=lane&15, row=quad*4+reg.
// ws peak usage ~196 MiB.

typedef __attribute__((ext_vector_type(8))) short short8;
typedef __attribute__((ext_vector_type(4))) float f32x4;
typedef unsigned short u16;

__device__ __forceinline__ u16 f2bf(float f) {
  union { float f; unsigned u; } v; v.f = f;
  unsigned r = v.u + 0x7fffu + ((v.u >> 16) & 1u);   // RNE
  return (u16)(r >> 16);
}
__device__ __forceinline__ float bf2f(u16 s) {
  union { unsigned u; float f; } v; v.u = ((unsigned)s) << 16; return v.f;
}

// ---------------------------------------------------------------- cast
__global__ void k_cast(const float* __restrict__ in, u16* __restrict__ out, int n4) {
  int i = blockIdx.x * 256 + threadIdx.x;
  if (i < n4) {
    float4 v = ((const float4*)in)[i];
    ushort4 o;
    o.x = f2bf(v.x); o.y = f2bf(v.y); o.z = f2bf(v.z); o.w = f2bf(v.w);
    ((ushort4*)out)[i] = o;
  }
}

// ---------------------------------------------------------------- GEMM
// C[M,N] = A[M,K](bf16,row-major) @ B[K,N](fp32,row-major, cast to bf16 in staging)
// 128x128 tile, BK=32, 256 threads (4 waves, each 64x64 = 4x4 MFMA tiles).
template<int BF16_OUT>
__global__ __launch_bounds__(256, 2) void k_gemm(
    const u16* __restrict__ A, const float* __restrict__ B,
    void* __restrict__ Cv, int M, int N, int K)
{
  __shared__ u16 As[128][40];   // [m][k], +8 pad (rows 80B: 16B-aligned, banks spread)
  __shared__ u16 Bs[128][40];   // [n][k] (B transposed in LDS for b128 frag reads)
  const int tid = threadIdx.x;
  const int wave = tid >> 6, lane = tid & 63;
  const int qd = lane >> 4, l = lane & 15;
  const int bn0 = blockIdx.x * 128, bm0 = blockIdx.y * 128;
  const int wrow = (wave >> 1) * 64, wcol = (wave & 1) * 64;
  const f32x4 fzero = {0.f, 0.f, 0.f, 0.f};

  f32x4 acc[4][4];
#pragma unroll
  for (int i = 0; i < 4; i++)
#pragma unroll
    for (int j = 0; j < 4; j++) acc[i][j] = fzero;

  const int a_row0 = tid >> 2;      // 0..63 (+64 on rep 1)
  const int a_cc   = tid & 3;       // 16B chunk within 32-elem row
  const int b_n    = tid & 127;
  const int b_h    = tid >> 7;      // k-half 0/1
  const int gn     = bn0 + b_n;
  const bool bvalid = (gn < N);

  for (int kt = 0; kt < K; kt += 32) {
    // ---- stage A (128x32 bf16): 2 x short8 per thread, coalesced
#pragma unroll
    for (int rep = 0; rep < 2; ++rep) {
      int row = a_row0 + rep * 64;
      const short8* src = (const short8*)(A + (size_t)(bm0 + row) * K + kt + a_cc * 8);
      *(short8*)&As[row][a_cc * 8] = *src;
    }
    // ---- stage B transposed (32x128 fp32 -> Bs[n][k] bf16): 16 scalar loads/thread
    float bv[16];
#pragma unroll
    for (int jj = 0; jj < 16; ++jj) {
      int kl = b_h * 16 + jj;
      bv[jj] = bvalid ? B[(size_t)(kt + kl) * N + gn] : 0.f;
    }
    u16 bs[16];
#pragma unroll
    for (int jj = 0; jj < 16; ++jj) bs[jj] = f2bf(bv[jj]);
    *(short8*)&Bs[b_n][b_h * 16]     = *(short8*)&bs[0];
    *(short8*)&Bs[b_n][b_h * 16 + 8] = *(short8*)&bs[8];
    __syncthreads();

    short8 af[4], bfr[4];
#pragma unroll
    for (int i = 0; i < 4; i++) af[i]  = *(const short8*)&As[wrow + i * 16 + l][qd * 8];
#pragma unroll
    for (int j = 0; j < 4; j++) bfr[j] = *(const short8*)&Bs[wcol + j * 16 + l][qd * 8];
#pragma unroll
    for (int i = 0; i < 4; i++)
#pragma unroll
      for (int j = 0; j < 4; j++)
        acc[i][j] = __builtin_amdgcn_mfma_f32_16x16x32_bf16(af[i], bfr[j], acc[i][j], 0, 0, 0);
    __syncthreads();
  }

  // ---- epilogue: C/D layout col=lane&15, row=quad*4+reg
#pragma unroll
  for (int i = 0; i < 4; i++) {
    int r = bm0 + wrow + i * 16 + qd * 4;
#pragma unroll
    for (int j = 0; j < 4; j++) {
      int c = bn0 + wcol + j * 16 + l;
      if (c < N) {
#pragma unroll
        for (int reg = 0; reg < 4; ++reg) {
          if (BF16_OUT)
            ((u16*)Cv)[(size_t)(r + reg) * N + c] = f2bf(acc[i][j][reg]);
          else
            ((float*)Cv)[(size_t)(r + reg) * N + c] = acc[i][j][reg];
        }
      }
    }
  }
}

// ---------------------------------------------------------------- rmsnorm
__global__ void k_rmsnorm(const float* __restrict__ in, int istride, int W,
                          const float* __restrict__ w, u16* __restrict__ out) {
  int row = blockIdx.x, tid = threadIdx.x;
  const float* x = in + (size_t)row * istride;
  float s = 0.f;
  for (int i = tid; i < W; i += 256) { float v = x[i]; s += v * v; }
#pragma unroll
  for (int o = 32; o; o >>= 1) s += __shfl_xor(s, o);
  __shared__ float red[4];
  if ((tid & 63) == 0) red[tid >> 6] = s;
  __syncthreads();
  float tot = red[0] + red[1] + red[2] + red[3];
  float sc = rsqrtf(tot / (float)W + 1e-6f);
  for (int i = tid; i < W; i += 256)
    out[(size_t)row * W + i] = f2bf(x[i] * sc * w[i]);
}

// ---------------------------------------------------------------- rope
// out[j]   = x[j]*cos(f_j) - x[j+32]*sin(f_j)
// out[j+32]= x[j+32]*cos(f_j) + x[j]*sin(f_j),  f_j = s * 10000^(-j/32)
__global__ void k_rope_q(u16* __restrict__ q) {   // in-place on (1024, 128*192)
  int idx = blockIdx.x * 256 + threadIdx.x;       // 1024*128*32
  int s = idx >> 12, r = idx & 4095, h = r >> 5, i = r & 31;
  float inv = expf((float)i * (-logf(10000.f) / 32.f));
  float ang = (float)s * inv, sn, cs;
  sincosf(ang, &sn, &cs);
  u16* p1 = q + (size_t)s * 24576 + h * 192 + 128 + i;
  u16* p2 = p1 + 32;
  float x1 = bf2f(*p1), x2 = bf2f(*p2);
  *p1 = f2bf(x1 * cs - x2 * sn);
  *p2 = f2bf(x2 * cs + x1 * sn);
}

__global__ void k_rope_k(const float* __restrict__ ckv, u16* __restrict__ kr) {
  int idx = blockIdx.x * 256 + threadIdx.x;       // 1024*32
  int s = idx >> 5, i = idx & 31;
  float inv = expf((float)i * (-logf(10000.f) / 32.f));
  float ang = (float)s * inv, sn, cs;
  sincosf(ang, &sn, &cs);
  const float* src = ckv + (size_t)s * 576 + 512;
  float x1 = src[i], x2 = src[i + 32];
  kr[s * 64 + i]      = f2bf(x1 * cs - x2 * sn);
  kr[s * 64 + 32 + i] = f2bf(x2 * cs + x1 * sn);
}

// ---------------------------------------------------------------- V transpose
// kv[s][h*256+128+dv] -> vt[h][dv][s]
__global__ void k_transpose_v(const u16* __restrict__ kv, u16* __restrict__ vt) {
  __shared__ u16 tile[32][33];
  int h = blockIdx.z, s0 = blockIdx.x * 32, d0 = blockIdx.y * 32;
  int tx = threadIdx.x, ty = threadIdx.y;   // 32 x 8
#pragma unroll
  for (int k2 = 0; k2 < 4; k2++) {
    int r = ty + k2 * 8;
    tile[r][tx] = kv[(size_t)(s0 + r) * 32768 + h * 256 + 128 + d0 + tx];
  }
  __syncthreads();
#pragma unroll
  for (int k2 = 0; k2 < 4; k2++) {
    int r = ty + k2 * 8;
    vt[(size_t)h * 131072 + (size_t)(d0 + r) * 1024 + s0 + tx] = tile[tx][r];
  }
}

// ---------------------------------------------------------------- attention
// One block = (head h, 64 q-rows). 4 waves x 16 q-rows. Iterate 16 kv-tiles of 64.
__global__ __launch_bounds__(256, 2) void k_attn(
    const u16* __restrict__ q,    // (1024, 128*192)
    const u16* __restrict__ kvn,  // (1024, 128*256): k_nope at h*256+0..127
    const u16* __restrict__ kr,   // (1024, 64) roped k_rope, shared across heads
    const u16* __restrict__ vt,   // (128, 128, 1024) V^T per head
    u16* __restrict__ o)          // (1024, 128*128)
{
  __shared__ u16 Ks[64][200];       // [kv][d], 192 used (nope|rope), 400B rows
  __shared__ u16 Vs[128][72];       // [dv][kv], 64 used, 144B rows
  __shared__ u16 Ps[4][16][64];     // per-wave P tile (q-local, kv)
  const int h = blockIdx.x, q0 = blockIdx.y * 64;
  const int tid = threadIdx.x, wave = tid >> 6, lane = tid & 63;
  const int qd = lane >> 4, l = lane & 15;
  const float scale = 0.07216878364870323f;   // 1/sqrt(192)
  const f32x4 fzero = {0.f, 0.f, 0.f, 0.f};

  // Q fragments in registers: rows q0+wave*16+l, d = kk*32 + qd*8 + 0..7
  short8 qf[6];
  {
    const u16* qp = q + (size_t)(q0 + wave * 16 + l) * 24576 + h * 192 + qd * 8;
#pragma unroll
    for (int kk = 0; kk < 6; kk++) qf[kk] = *(const short8*)(qp + kk * 32);
  }

  f32x4 Of[8];
#pragma unroll
  for (int jt = 0; jt < 8; jt++) Of[jt] = fzero;
  float m_i[4] = {-1e30f, -1e30f, -1e30f, -1e30f};
  float l_i[4] = {0.f, 0.f, 0.f, 0.f};

  for (int kt = 0; kt < 16; ++kt) {
    const int kv0 = kt * 64;
    __syncthreads();
    // stage K tile (64 x 192): 1536 16B-chunks, 6 per thread
#pragma unroll
    for (int it = 0; it < 6; ++it) {
      int ci = it * 256 + tid;
      int r = ci / 24, c = ci % 24;
      int col0 = c * 8;
      const u16* src = (col0 < 128)
          ? kvn + (size_t)(kv0 + r) * 32768 + h * 256 + col0
          : kr + (size_t)(kv0 + r) * 64 + (col0 - 128);
      *(short8*)&Ks[r][col0] = *(const short8*)src;
    }
    // stage V^T tile (128 dv x 64 kv): 1024 chunks, 4 per thread
#pragma unroll
    for (int it = 0; it < 4; ++it) {
      int ci = it * 256 + tid;
      int dv = ci >> 3, c = ci & 7;
      *(short8*)&Vs[dv][c * 8] =
          *(const short8*)(vt + (size_t)h * 131072 + (size_t)dv * 1024 + kv0 + c * 8);
    }
    __syncthreads();

    // S = Q K^T  (16 x 64 per wave)
    f32x4 sf[4];
#pragma unroll
    for (int j = 0; j < 4; j++) sf[j] = fzero;
#pragma unroll
    for (int kk = 0; kk < 6; kk++)
#pragma unroll
      for (int j = 0; j < 4; j++) {
        short8 bf = *(const short8*)&Ks[j * 16 + l][kk * 32 + qd * 8];
        sf[j] = __builtin_amdgcn_mfma_f32_16x16x32_bf16(qf[kk], bf, sf[j], 0, 0, 0);
      }
#pragma unroll
    for (int j = 0; j < 4; j++) sf[j] *= scale;

    // online softmax (fp32). Row = qd*4+reg lives in the 16 lanes sharing qd.
#pragma unroll
    for (int reg = 0; reg < 4; ++reg) {
      float mx = fmaxf(fmaxf(sf[0][reg], sf[1][reg]), fmaxf(sf[2][reg], sf[3][reg]));
#pragma unroll
      for (int off = 1; off < 16; off <<= 1) mx = fmaxf(mx, __shfl_xor(mx, off));
      float mnew = fmaxf(m_i[reg], mx);
      float alpha = expf(m_i[reg] - mnew);
      m_i[reg] = mnew;
      float rs = 0.f;
#pragma unroll
      for (int j = 0; j < 4; j++) {
        float p = expf(sf[j][reg] - mnew);
        rs += p;
        Ps[wave][qd * 4 + reg][j * 16 + l] = f2bf(p);   // C-layout -> LDS
      }
#pragma unroll
      for (int off = 1; off < 16; off <<= 1) rs += __shfl_xor(rs, off);
      l_i[reg] = l_i[reg] * alpha + rs;
#pragma unroll
      for (int jt = 0; jt < 8; jt++) Of[jt][reg] *= alpha;
    }

    // O += P V   (P via LDS round-trip into A-operand layout; same-wave DS is in-order)
#pragma unroll
    for (int ks = 0; ks < 2; ++ks) {
      short8 pf = *(const short8*)&Ps[wave][l][ks * 32 + qd * 8];
#pragma unroll
      for (int jt = 0; jt < 8; jt++) {
        short8 vf = *(const short8*)&Vs[jt * 16 + l][ks * 32 + qd * 8];
        Of[jt] = __builtin_amdgcn_mfma_f32_16x16x32_bf16(pf, vf, Of[jt], 0, 0, 0);
      }
    }
  }

  // epilogue: O /= l, write (s, h*128+dv) bf16
#pragma unroll
  for (int reg = 0; reg < 4; ++reg) {
    float inv_l = 1.f / l_i[reg];
    int row = q0 + wave * 16 + qd * 4 + reg;
#pragma unroll
    for (int jt = 0; jt < 8; jt++)
      o[(size_t)row * 16384 + h * 128 + jt * 16 + l] = f2bf(Of[jt][reg] * inv_l);
  }
}

// ---------------------------------------------------------------- launch
extern "C" void kernel_launch(void* const* d_in, const int* in_sizes, int n_in,
                              void* d_out, int out_size, void* d_ws, size_t ws_size,
                              hipStream_t stream)
{
  const float* hidden = (const float*)d_in[0];
  const float* Wq_c   = (const float*)d_in[1];
  const float* q_nw   = (const float*)d_in[2];
  const float* Wq_d   = (const float*)d_in[3];
  const float* Wkv_c  = (const float*)d_in[4];
  const float* kv_nw  = (const float*)d_in[5];
  const float* Wkv_d  = (const float*)d_in[6];
  const float* Wo     = (const float*)d_in[7];

  float* out = (float*)d_out;                       // (1024, 5120)
  float* ckv = out + (size_t)1024 * 5120;           // (1024, 576)  output #2

  char* ws = (char*)d_ws;
  u16*   h_bf  = (u16*)ws;   ws += (size_t)1024 * 5120 * 2;
  float* q_c   = (float*)ws; ws += (size_t)1024 * 1536 * 4;
  u16*   q_n   = (u16*)ws;   ws += (size_t)1024 * 1536 * 2;
  u16*   qbuf  = (u16*)ws;   ws += (size_t)1024 * 24576 * 2;
  u16*   kv_n  = (u16*)ws;   ws += (size_t)1024 * 512 * 2;
  u16*   kvbuf = (u16*)ws;   ws += (size_t)1024 * 32768 * 2;
  u16*   krope = (u16*)ws;   ws += (size_t)1024 * 64 * 2;
  u16*   vt    = (u16*)ws;   ws += (size_t)128 * 128 * 1024 * 2;
  u16*   attno = (u16*)ws;   ws += (size_t)1024 * 16384 * 2;
  // peak ws: ~196 MiB

  dim3 b256(256);
  k_cast<<<5120, b256, 0, stream>>>(hidden, h_bf, 1024 * 5120 / 4);

  k_gemm<0><<<dim3(12, 8),  b256, 0, stream>>>(h_bf, Wq_c,  q_c, 1024, 1536, 5120);
  k_gemm<0><<<dim3(5, 8),   b256, 0, stream>>>(h_bf, Wkv_c, ckv, 1024, 576,  5120);

  k_rmsnorm<<<1024, b256, 0, stream>>>(q_c, 1536, 1536, q_nw, q_n);
  k_rmsnorm<<<1024, b256, 0, stream>>>(ckv, 576,  512,  kv_nw, kv_n);

  k_gemm<1><<<dim3(192, 8), b256, 0, stream>>>(q_n,  Wq_d,  qbuf,  1024, 24576, 1536);
  k_gemm<1><<<dim3(256, 8), b256, 0, stream>>>(kv_n, Wkv_d, kvbuf, 1024, 32768, 512);

  k_rope_q<<<16384, b256, 0, stream>>>(qbuf);
  k_rope_k<<<128,   b256, 0, stream>>>(ckv, krope);

  k_transpose_v<<<dim3(32, 4, 128), dim3(32, 8), 0, stream>>>(kvbuf, vt);

  k_attn<<<dim3(128, 16), b256, 0, stream>>>(qbuf, kvbuf, krope, vt, attno);

  k_gemm<0><<<dim3(40, 8), b256, 0, stream>>>(attno, Wo, out, 1024, 5120, 16384);
}

// Round 2
// 1618.459 us; speedup vs baseline: 1.3768x; 1.3768x over previous
//
#include <hip/hip_runtime.h>

// MLA forward, MI355X gfx950. Round 2: m97-style GEMMs.
// H=128 DN=128 DR=64 DV=128 RQ=1536 RKV=512 HSZ=5120 S=1024
//
// Changes vs round 1:
//  - All 5 weight matrices cast fp32[K][N] -> bf16 WT[Npad][K] once per call (k_wt).
//  - k_gemm_bt: 128x128 tile, BK=32, A and B^T staged with
//    global_load_lds dwordx4 (16B) into unpadded [128][32] LDS, ds_read_b128
//    fragments, 16 MFMA 16x16x32 per wave per K-tile (the verified m97 structure).
//  - Split-K + fp32 atomicAdd for grid-starved GEMMs (q-down x4, kv-down x8,
//    out-proj x4 -> 1280 blocks). d_out / q_c zero-initialized by k_zero.
// Attention / rmsnorm / rope / v-transpose unchanged from round 1 (passed).

typedef __attribute__((ext_vector_type(8))) short short8;
typedef __attribute__((ext_vector_type(4))) float f32x4;
typedef unsigned short u16;

__device__ __forceinline__ u16 f2bf(float f) {
  union { float f; unsigned u; } v; v.f = f;
  unsigned r = v.u + 0x7fffu + ((v.u >> 16) & 1u);   // RNE
  return (u16)(r >> 16);
}
__device__ __forceinline__ float bf2f(u16 s) {
  union { unsigned u; float f; } v; v.u = ((unsigned)s) << 16; return v.f;
}

__device__ __forceinline__ void gl_lds16(const u16* g, u16* l) {
  __builtin_amdgcn_global_load_lds(
      (const __attribute__((address_space(1))) void*)g,
      (__attribute__((address_space(3))) void*)l,
      16, 0, 0);
}

// ---------------------------------------------------------------- zero fill
__global__ void k_zero(float* __restrict__ p, int n4) {
  int i = blockIdx.x * 256 + threadIdx.x;
  if (i < n4) ((float4*)p)[i] = make_float4(0.f, 0.f, 0.f, 0.f);
}

// ---------------------------------------------------------------- cast
__global__ void k_cast(const float* __restrict__ in, u16* __restrict__ out, int n4) {
  int i = blockIdx.x * 256 + threadIdx.x;
  if (i < n4) {
    float4 v = ((const float4*)in)[i];
    ushort4 o;
    o.x = f2bf(v.x); o.y = f2bf(v.y); o.z = f2bf(v.z); o.w = f2bf(v.w);
    ((ushort4*)out)[i] = o;
  }
}

// ---------------------------------------------------------------- weight cast+transpose
// W fp32 [K][N] -> WT bf16 [Npad][K]; pad rows (n>=N) zeroed.
__global__ void k_wt(const float* __restrict__ W, u16* __restrict__ WT,
                     int K, int N) {
  __shared__ u16 t[32][33];
  int n0 = blockIdx.x * 32, k0 = blockIdx.y * 32;
  int tx = threadIdx.x, ty = threadIdx.y;   // 32 x 8
#pragma unroll
  for (int r = 0; r < 4; r++) {
    int kl = ty + r * 8, n = n0 + tx;
    float v = (n < N) ? W[(size_t)(k0 + kl) * N + n] : 0.f;
    t[kl][tx] = f2bf(v);
  }
  __syncthreads();
#pragma unroll
  for (int r = 0; r < 4; r++) {
    int nl = ty + r * 8;
    WT[(size_t)(n0 + nl) * K + k0 + tx] = t[tx][nl];
  }
}

// ---------------------------------------------------------------- GEMM (m97 structure)
// C[M,N] = A[M,K](bf16 row-major) @ BT[Npad,K](bf16, B transposed)
// 128x128 tile, BK=32, 256 threads = 4 waves, each 64x64 (4x4 MFMA 16x16x32).
// OUT_MODE: 0 = fp32 store, 1 = bf16 store, 2 = fp32 atomicAdd (split-K).
template<int OUT_MODE>
__global__ __launch_bounds__(256) void k_gemm_bt(
    const u16* __restrict__ A, const u16* __restrict__ BT,
    void* __restrict__ Cv, int M, int N, int K, int kChunk)
{
  __shared__ u16 As[128 * 32];   // [m][k], 64B rows, contiguous (global_load_lds)
  __shared__ u16 Bs[128 * 32];   // [n][k]
  const int tid = threadIdx.x;
  const int wave = tid >> 6, lane = tid & 63;
  const int qd = lane >> 4, l = lane & 15;
  const int bn0 = blockIdx.x * 128, bm0 = blockIdx.y * 128;
  const int k0 = blockIdx.z * kChunk;
  const int wrow = (wave >> 1) * 64, wcol = (wave & 1) * 64;
  const f32x4 fzero = {0.f, 0.f, 0.f, 0.f};

  f32x4 acc[4][4];
#pragma unroll
  for (int i = 0; i < 4; i++)
#pragma unroll
    for (int j = 0; j < 4; j++) acc[i][j] = fzero;

  // staging geometry: 16B chunk per lane; wave w round r covers rows r*64+w*16+lane/4
  const int sm = wave * 16 + (lane >> 2);   // source row 0..63
  const int sc = (lane & 3) * 8;            // source col (elements)
  const u16* a0 = A  + (size_t)(bm0 + sm) * K + sc;
  const u16* a1 = A  + (size_t)(bm0 + 64 + sm) * K + sc;
  const u16* b0 = BT + (size_t)(bn0 + sm) * K + sc;
  const u16* b1 = BT + (size_t)(bn0 + 64 + sm) * K + sc;
  u16* aD0 = As + wave * 512;          // wave-uniform LDS dest (u16 units)
  u16* aD1 = As + 2048 + wave * 512;
  u16* bD0 = Bs + wave * 512;
  u16* bD1 = Bs + 2048 + wave * 512;

  const int kEnd = k0 + kChunk;
  for (int kt = k0; kt < kEnd; kt += 32) {
    gl_lds16(a0 + kt, aD0);
    gl_lds16(a1 + kt, aD1);
    gl_lds16(b0 + kt, bD0);
    gl_lds16(b1 + kt, bD1);
    __syncthreads();   // vmcnt(0) drain + barrier

    short8 af[4], bfr[4];
#pragma unroll
    for (int i = 0; i < 4; i++) af[i]  = *(const short8*)&As[(wrow + i * 16 + l) * 32 + qd * 8];
#pragma unroll
    for (int j = 0; j < 4; j++) bfr[j] = *(const short8*)&Bs[(wcol + j * 16 + l) * 32 + qd * 8];
#pragma unroll
    for (int i = 0; i < 4; i++)
#pragma unroll
      for (int j = 0; j < 4; j++)
        acc[i][j] = __builtin_amdgcn_mfma_f32_16x16x32_bf16(af[i], bfr[j], acc[i][j], 0, 0, 0);
    __syncthreads();   // before next tile overwrites LDS
  }

  // epilogue: C/D layout col=lane&15, row=quad*4+reg
#pragma unroll
  for (int i = 0; i < 4; i++) {
    int r = bm0 + wrow + i * 16 + qd * 4;
#pragma unroll
    for (int j = 0; j < 4; j++) {
      int c = bn0 + wcol + j * 16 + l;
      if (c < N) {
#pragma unroll
        for (int reg = 0; reg < 4; ++reg) {
          if (OUT_MODE == 1)
            ((u16*)Cv)[(size_t)(r + reg) * N + c] = f2bf(acc[i][j][reg]);
          else if (OUT_MODE == 0)
            ((float*)Cv)[(size_t)(r + reg) * N + c] = acc[i][j][reg];
          else
            atomicAdd(&((float*)Cv)[(size_t)(r + reg) * N + c], acc[i][j][reg]);
        }
      }
    }
  }
}

// ---------------------------------------------------------------- rmsnorm
__global__ void k_rmsnorm(const float* __restrict__ in, int istride, int W,
                          const float* __restrict__ w, u16* __restrict__ out) {
  int row = blockIdx.x, tid = threadIdx.x;
  const float* x = in + (size_t)row * istride;
  float s = 0.f;
  for (int i = tid; i < W; i += 256) { float v = x[i]; s += v * v; }
#pragma unroll
  for (int o = 32; o; o >>= 1) s += __shfl_xor(s, o);
  __shared__ float red[4];
  if ((tid & 63) == 0) red[tid >> 6] = s;
  __syncthreads();
  float tot = red[0] + red[1] + red[2] + red[3];
  float sc = rsqrtf(tot / (float)W + 1e-6f);
  for (int i = tid; i < W; i += 256)
    out[(size_t)row * W + i] = f2bf(x[i] * sc * w[i]);
}

// ---------------------------------------------------------------- rope
__global__ void k_rope_q(u16* __restrict__ q) {   // in-place on (1024, 128*192)
  int idx = blockIdx.x * 256 + threadIdx.x;       // 1024*128*32
  int s = idx >> 12, r = idx & 4095, h = r >> 5, i = r & 31;
  float inv = expf((float)i * (-logf(10000.f) / 32.f));
  float ang = (float)s * inv, sn, cs;
  sincosf(ang, &sn, &cs);
  u16* p1 = q + (size_t)s * 24576 + h * 192 + 128 + i;
  u16* p2 = p1 + 32;
  float x1 = bf2f(*p1), x2 = bf2f(*p2);
  *p1 = f2bf(x1 * cs - x2 * sn);
  *p2 = f2bf(x2 * cs + x1 * sn);
}

__global__ void k_rope_k(const float* __restrict__ ckv, u16* __restrict__ kr) {
  int idx = blockIdx.x * 256 + threadIdx.x;       // 1024*32
  int s = idx >> 5, i = idx & 31;
  float inv = expf((float)i * (-logf(10000.f) / 32.f));
  float ang = (float)s * inv, sn, cs;
  sincosf(ang, &sn, &cs);
  const float* src = ckv + (size_t)s * 576 + 512;
  float x1 = src[i], x2 = src[i + 32];
  kr[s * 64 + i]      = f2bf(x1 * cs - x2 * sn);
  kr[s * 64 + 32 + i] = f2bf(x2 * cs + x1 * sn);
}

// ---------------------------------------------------------------- V transpose
// kv[s][h*256+128+dv] -> vt[h][dv][s]
__global__ void k_transpose_v(const u16* __restrict__ kv, u16* __restrict__ vt) {
  __shared__ u16 tile[32][33];
  int h = blockIdx.z, s0 = blockIdx.x * 32, d0 = blockIdx.y * 32;
  int tx = threadIdx.x, ty = threadIdx.y;   // 32 x 8
#pragma unroll
  for (int k2 = 0; k2 < 4; k2++) {
    int r = ty + k2 * 8;
    tile[r][tx] = kv[(size_t)(s0 + r) * 32768 + h * 256 + 128 + d0 + tx];
  }
  __syncthreads();
#pragma unroll
  for (int k2 = 0; k2 < 4; k2++) {
    int r = ty + k2 * 8;
    vt[(size_t)h * 131072 + (size_t)(d0 + r) * 1024 + s0 + tx] = tile[tx][r];
  }
}

// ---------------------------------------------------------------- attention
// One block = (head h, 64 q-rows). 4 waves x 16 q-rows. Iterate 16 kv-tiles of 64.
__global__ __launch_bounds__(256, 2) void k_attn(
    const u16* __restrict__ q,    // (1024, 128*192)
    const u16* __restrict__ kvn,  // (1024, 128*256): k_nope at h*256+0..127
    const u16* __restrict__ kr,   // (1024, 64) roped k_rope, shared across heads
    const u16* __restrict__ vt,   // (128, 128, 1024) V^T per head
    u16* __restrict__ o)          // (1024, 128*128)
{
  __shared__ u16 Ks[64][200];
  __shared__ u16 Vs[128][72];
  __shared__ u16 Ps[4][16][64];
  const int h = blockIdx.x, q0 = blockIdx.y * 64;
  const int tid = threadIdx.x, wave = tid >> 6, lane = tid & 63;
  const int qd = lane >> 4, l = lane & 15;
  const float scale = 0.07216878364870323f;   // 1/sqrt(192)
  const f32x4 fzero = {0.f, 0.f, 0.f, 0.f};

  short8 qf[6];
  {
    const u16* qp = q + (size_t)(q0 + wave * 16 + l) * 24576 + h * 192 + qd * 8;
#pragma unroll
    for (int kk = 0; kk < 6; kk++) qf[kk] = *(const short8*)(qp + kk * 32);
  }

  f32x4 Of[8];
#pragma unroll
  for (int jt = 0; jt < 8; jt++) Of[jt] = fzero;
  float m_i[4] = {-1e30f, -1e30f, -1e30f, -1e30f};
  float l_i[4] = {0.f, 0.f, 0.f, 0.f};

  for (int kt = 0; kt < 16; ++kt) {
    const int kv0 = kt * 64;
    __syncthreads();
#pragma unroll
    for (int it = 0; it < 6; ++it) {
      int ci = it * 256 + tid;
      int r = ci / 24, c = ci % 24;
      int col0 = c * 8;
      const u16* src = (col0 < 128)
          ? kvn + (size_t)(kv0 + r) * 32768 + h * 256 + col0
          : kr + (size_t)(kv0 + r) * 64 + (col0 - 128);
      *(short8*)&Ks[r][col0] = *(const short8*)src;
    }
#pragma unroll
    for (int it = 0; it < 4; ++it) {
      int ci = it * 256 + tid;
      int dv = ci >> 3, c = ci & 7;
      *(short8*)&Vs[dv][c * 8] =
          *(const short8*)(vt + (size_t)h * 131072 + (size_t)dv * 1024 + kv0 + c * 8);
    }
    __syncthreads();

    f32x4 sf[4];
#pragma unroll
    for (int j = 0; j < 4; j++) sf[j] = fzero;
#pragma unroll
    for (int kk = 0; kk < 6; kk++)
#pragma unroll
      for (int j = 0; j < 4; j++) {
        short8 bf = *(const short8*)&Ks[j * 16 + l][kk * 32 + qd * 8];
        sf[j] = __builtin_amdgcn_mfma_f32_16x16x32_bf16(qf[kk], bf, sf[j], 0, 0, 0);
      }
#pragma unroll
    for (int j = 0; j < 4; j++) sf[j] *= scale;

#pragma unroll
    for (int reg = 0; reg < 4; ++reg) {
      float mx = fmaxf(fmaxf(sf[0][reg], sf[1][reg]), fmaxf(sf[2][reg], sf[3][reg]));
#pragma unroll
      for (int off = 1; off < 16; off <<= 1) mx = fmaxf(mx, __shfl_xor(mx, off));
      float mnew = fmaxf(m_i[reg], mx);
      float alpha = expf(m_i[reg] - mnew);
      m_i[reg] = mnew;
      float rs = 0.f;
#pragma unroll
      for (int j = 0; j < 4; j++) {
        float p = expf(sf[j][reg] - mnew);
        rs += p;
        Ps[wave][qd * 4 + reg][j * 16 + l] = f2bf(p);
      }
#pragma unroll
      for (int off = 1; off < 16; off <<= 1) rs += __shfl_xor(rs, off);
      l_i[reg] = l_i[reg] * alpha + rs;
#pragma unroll
      for (int jt = 0; jt < 8; jt++) Of[jt][reg] *= alpha;
    }

#pragma unroll
    for (int ks = 0; ks < 2; ++ks) {
      short8 pf = *(const short8*)&Ps[wave][l][ks * 32 + qd * 8];
#pragma unroll
      for (int jt = 0; jt < 8; jt++) {
        short8 vf = *(const short8*)&Vs[jt * 16 + l][ks * 32 + qd * 8];
        Of[jt] = __builtin_amdgcn_mfma_f32_16x16x32_bf16(pf, vf, Of[jt], 0, 0, 0);
      }
    }
  }

#pragma unroll
  for (int reg = 0; reg < 4; ++reg) {
    float inv_l = 1.f / l_i[reg];
    int row = q0 + wave * 16 + qd * 4 + reg;
#pragma unroll
    for (int jt = 0; jt < 8; jt++)
      o[(size_t)row * 16384 + h * 128 + jt * 16 + l] = f2bf(Of[jt][reg] * inv_l);
  }
}

// ---------------------------------------------------------------- launch
extern "C" void kernel_launch(void* const* d_in, const int* in_sizes, int n_in,
                              void* d_out, int out_size, void* d_ws, size_t ws_size,
                              hipStream_t stream)
{
  const float* hidden = (const float*)d_in[0];
  const float* Wq_c   = (const float*)d_in[1];
  const float* q_nw   = (const float*)d_in[2];
  const float* Wq_d   = (const float*)d_in[3];
  const float* Wkv_c  = (const float*)d_in[4];
  const float* kv_nw  = (const float*)d_in[5];
  const float* Wkv_d  = (const float*)d_in[6];
  const float* Wo     = (const float*)d_in[7];

  float* out = (float*)d_out;                       // (1024, 5120)
  float* ckv = out + (size_t)1024 * 5120;           // (1024, 576)  output #2

  char* ws = (char*)d_ws;
  u16*   h_bf  = (u16*)ws;   ws += (size_t)1024 * 5120 * 2;
  float* q_c   = (float*)ws; ws += (size_t)1024 * 1536 * 4;
  u16*   q_n   = (u16*)ws;   ws += (size_t)1024 * 1536 * 2;
  u16*   qbuf  = (u16*)ws;   ws += (size_t)1024 * 24576 * 2;
  u16*   kv_n  = (u16*)ws;   ws += (size_t)1024 * 512 * 2;
  u16*   kvbuf = (u16*)ws;   ws += (size_t)1024 * 32768 * 2;
  u16*   krope = (u16*)ws;   ws += (size_t)1024 * 64 * 2;
  u16*   vt    = (u16*)ws;   ws += (size_t)128 * 128 * 1024 * 2;
  u16*   attno = (u16*)ws;   ws += (size_t)1024 * 16384 * 2;
  // transposed bf16 weights [Npad][K]:
  u16*   wtqc  = (u16*)ws;   ws += (size_t)1536 * 5120 * 2;
  u16*   wtkvc = (u16*)ws;   ws += (size_t)640 * 5120 * 2;
  u16*   wtqd  = (u16*)ws;   ws += (size_t)24576 * 1536 * 2;
  u16*   wtkvd = (u16*)ws;   ws += (size_t)32768 * 512 * 2;
  u16*   wto   = (u16*)ws;   ws += (size_t)5120 * 16384 * 2;
  // peak ws ~481 MiB

  dim3 b256(256), bwt(32, 8);

  // zero atomic-accumulated outputs: d_out (out+ckv) and q_c
  k_zero<<<5696, b256, 0, stream>>>(out, (1024 * 5120 + 1024 * 576) / 4);
  k_zero<<<1536, b256, 0, stream>>>(q_c, 1024 * 1536 / 4);

  // weight cast+transpose
  k_wt<<<dim3(48, 160),  bwt, 0, stream>>>(Wq_c,  wtqc,  5120, 1536);
  k_wt<<<dim3(20, 160),  bwt, 0, stream>>>(Wkv_c, wtkvc, 5120, 576);
  k_wt<<<dim3(768, 48),  bwt, 0, stream>>>(Wq_d,  wtqd,  1536, 24576);
  k_wt<<<dim3(1024, 16), bwt, 0, stream>>>(Wkv_d, wtkvd, 512,  32768);
  k_wt<<<dim3(160, 512), bwt, 0, stream>>>(Wo,    wto,   16384, 5120);

  k_cast<<<5120, b256, 0, stream>>>(hidden, h_bf, 1024 * 5120 / 4);

  // q-down (split-K x4) and kv-down (split-K x8), fp32 atomic accumulate
  k_gemm_bt<2><<<dim3(12, 8, 4), b256, 0, stream>>>(h_bf, wtqc,  q_c, 1024, 1536, 5120, 1280);
  k_gemm_bt<2><<<dim3(5, 8, 8),  b256, 0, stream>>>(h_bf, wtkvc, ckv, 1024, 576,  5120, 640);

  k_rmsnorm<<<1024, b256, 0, stream>>>(q_c, 1536, 1536, q_nw, q_n);
  k_rmsnorm<<<1024, b256, 0, stream>>>(ckv, 576,  512,  kv_nw, kv_n);

  // up-projections, bf16 out
  k_gemm_bt<1><<<dim3(192, 8, 1), b256, 0, stream>>>(q_n,  wtqd,  qbuf,  1024, 24576, 1536, 1536);
  k_gemm_bt<1><<<dim3(256, 8, 1), b256, 0, stream>>>(kv_n, wtkvd, kvbuf, 1024, 32768, 512,  512);

  k_rope_q<<<16384, b256, 0, stream>>>(qbuf);
  k_rope_k<<<128,   b256, 0, stream>>>(ckv, krope);

  k_transpose_v<<<dim3(32, 4, 128), dim3(32, 8), 0, stream>>>(kvbuf, vt);

  k_attn<<<dim3(128, 16), b256, 0, stream>>>(qbuf, kvbuf, krope, vt, attno);

  // out-proj (split-K x4), fp32 atomic accumulate into d_out
  k_gemm_bt<2><<<dim3(40, 8, 4), b256, 0, stream>>>(attno, wto, out, 1024, 5120, 16384, 4096);
}